// Round 1
// 272.446 us; speedup vs baseline: 1.0013x; 1.0013x over previous
//
#include <hip/hip_runtime.h>
#include <hip/hip_bf16.h>
#include <math.h>

typedef __hip_bfloat16 bf16;
typedef __attribute__((ext_vector_type(4))) float f32x4;
typedef __attribute__((ext_vector_type(8))) short s16x8;

typedef const __attribute__((address_space(1))) void gvoid_t;
typedef __attribute__((address_space(3))) void lvoid_t;

__device__ __forceinline__ void gload16(const void* g, void* l) {
  // async global->LDS, 16B/lane; LDS dest is wave-uniform base + lane*16
  __builtin_amdgcn_global_load_lds((gvoid_t*)g, (lvoid_t*)l, 16, 0, 0);
}
__device__ __forceinline__ unsigned short f2b(float f) {
  bf16 h = __float2bfloat16(f);
  return *(unsigned short*)&h;
}

// ---------------- prep: x = concat(patches, positions) -> bf16 [16384][832]
__global__ __launch_bounds__(256) void prep_x(const float* __restrict__ patches,
                                              const float* __restrict__ positions,
                                              bf16* __restrict__ xb) {
  const long long row = blockIdx.x;
  const int c = threadIdx.x;
  const bool lo = (c < 192);
  const bool hi = (c >= 192) && (c < 208);
  const float* src = lo ? (patches + row * 768 + c * 4)
                        : (positions + row * 64 + (c - 192) * 4);
  if (lo || hi) {
    float4 v = *(const float4*)src;
    const int dst = lo ? (c * 4) : (768 + (c - 192) * 4);
    uint2 w;
    w.x = (unsigned int)f2b(v.x) | ((unsigned int)f2b(v.y) << 16);
    w.y = (unsigned int)f2b(v.z) | ((unsigned int)f2b(v.w) << 16);
    *(uint2*)(xb + row * 832 + dst) = w;
  }
}

// ---------------- prep: Wt[z*512+n][k] = W_z[k][n] bf16 (832x512 -> 512x832)
__global__ __launch_bounds__(256) void prep_w(const float* __restrict__ Wq,
                                              const float* __restrict__ Wk,
                                              const float* __restrict__ Wv,
                                              bf16* __restrict__ Wt) {
  __shared__ float tile[32][33];
  const int z = blockIdx.z;
  const float* W = (z == 0) ? Wq : (z == 1) ? Wk : Wv;
  bf16* T = Wt + (long long)z * 512 * 832;
  const int n0 = blockIdx.x * 32;
  const int k0 = blockIdx.y * 32;
  const int tx = threadIdx.x, ty = threadIdx.y;  // (32,8)
  #pragma unroll
  for (int i = 0; i < 32; i += 8)
    tile[ty + i][tx] = W[(long long)(k0 + ty + i) * 512 + n0 + tx];
  __syncthreads();
  #pragma unroll
  for (int i = 0; i < 32; i += 8)
    T[(long long)(n0 + ty + i) * 832 + k0 + tx] = __float2bfloat16(tile[tx][ty + i]);
}

// ---------------- fused QKV projection: [16384,832] x [1536,832]^T
__global__ __launch_bounds__(256) void gemm_qkv(
    const bf16* __restrict__ xb, const bf16* __restrict__ Wt,
    const float* __restrict__ bq, const float* __restrict__ bk,
    const float* __restrict__ bv,
    bf16* __restrict__ qk, bf16* __restrict__ vt) {
  __shared__ bf16 As[128 * 64];
  __shared__ bf16 Bs[128 * 64];
  const int tid = threadIdx.x;
  const int wave = tid >> 6, lane = tid & 63;
  const int llo = lane & 15, lhi = lane >> 4;
  const int wm = wave >> 1, wn = wave & 1;

  const unsigned int lin = blockIdx.x;        // 1536 blocks
  const unsigned int xcd = lin & 7u, idx = lin >> 3;
  const unsigned int g = xcd * 192u + idx;
  const unsigned int bm_t = g / 12u;          // 0..127
  const unsigned int bn_t = g - bm_t * 12u;   // 0..11
  const int row0 = (int)bm_t * 128;
  const int col0 = (int)bn_t * 128;
  const int z = col0 >> 9;

  f32x4 acc[4][4] = {};

  for (int kt = 0; kt < 832; kt += 64) {
    #pragma unroll
    for (int i = 0; i < 4; i++) {
      const int c = i * 256 + tid;
      const int r = c >> 3, cc = c & 7;
      const int kk = (cc ^ (r & 7)) << 3;     // XOR swizzle via global addr
      gload16(xb + ((long long)(row0 + r) * 832 + kt + kk),
              (char*)As + (long long)(i * 256 + wave * 64) * 16);
      gload16(Wt + ((long long)(col0 + r) * 832 + kt + kk),
              (char*)Bs + (long long)(i * 256 + wave * 64) * 16);
    }
    __syncthreads();
    #pragma unroll
    for (int k0 = 0; k0 < 64; k0 += 32) {
      const int xk = ((((k0 >> 3) + lhi) ^ (llo & 7)) << 3);
      s16x8 af[4], bfr[4];
      #pragma unroll
      for (int mf = 0; mf < 4; mf++)
        af[mf] = *(const s16x8*)&As[(wm * 64 + mf * 16 + llo) * 64 + xk];
      #pragma unroll
      for (int nf = 0; nf < 4; nf++)
        bfr[nf] = *(const s16x8*)&Bs[(wn * 64 + nf * 16 + llo) * 64 + xk];
      #pragma unroll
      for (int mf = 0; mf < 4; mf++)
        #pragma unroll
        for (int nf = 0; nf < 4; nf++)
          acc[mf][nf] = __builtin_amdgcn_mfma_f32_16x16x32_bf16(
              af[mf], bfr[nf], acc[mf][nf], 0, 0, 0);
    }
    __syncthreads();
  }

  if (z < 2) {
    const float* bias = z ? bk : bq;
    bf16* outp = qk + (long long)z * 16384 * 512;
    #pragma unroll
    for (int mf = 0; mf < 4; mf++)
      #pragma unroll
      for (int nf = 0; nf < 4; nf++) {
        const int c = (col0 & 511) + wn * 64 + nf * 16 + llo;
        const int grow0 = row0 + wm * 64 + mf * 16 + lhi * 4;
        const float bb = bias[c];
        #pragma unroll
        for (int r = 0; r < 4; r++)
          outp[(long long)(grow0 + r) * 512 + c] =
              __float2bfloat16(acc[mf][nf][r] + bb);
      }
  } else {
    #pragma unroll
    for (int mf = 0; mf < 4; mf++)
      #pragma unroll
      for (int nf = 0; nf < 4; nf++) {
        const int c = (col0 & 511) + wn * 64 + nf * 16 + llo;
        const int grow0 = row0 + wm * 64 + mf * 16 + lhi * 4;
        const int b = grow0 >> 11, j = grow0 & 2047;
        const float bb = bv[c];
        uint2 w;
        w.x = (unsigned int)f2b(acc[mf][nf][0] + bb) |
              ((unsigned int)f2b(acc[mf][nf][1] + bb) << 16);
        w.y = (unsigned int)f2b(acc[mf][nf][2] + bb) |
              ((unsigned int)f2b(acc[mf][nf][3] + bb) << 16);
        *(uint2*)(vt + (long long)b * 512 * 2048 + (long long)c * 2048 + j) = w;
      }
  }
}

// ---------------- scores+exp: 256x256 tile, 8 waves, 8-phase counted-vmcnt
// schedule (T3+T4+T5 on top of the proven 0-conflict XOR swizzle).
// Derived half-tile schedule (half = 128 rows x 64 k = 16 KB = 2 gloads/wave):
//   phase: P1       P2       P3       P4       P5       P6       P7       P8
//   stage: B1h1(t1) A1h1(t1) A0h0(t2) B0h0(t2) B0h1(t2) A0h1(t2) A1h0(t3) B1h0(t3)
//   wait : vm(8)    vm(8)    --       vm(8)    vm(8)    vm(8)    --       vm(8)
// Quadrant order (r0c0, r0c1, r1c0, r1c1) with reg-held frags => all LDS
// reads of a tile finish by P3, making each stage slot write-after-read safe
// (>=2 barriers after last read). vmcnt(8) always retires exactly the
// half-tiles the NEXT phase reads; >=4 half-tiles stay in flight (never 0).
#define VMW8 asm volatile("s_waitcnt vmcnt(8)" ::: "memory")
#define PBAR do { __builtin_amdgcn_s_barrier(); __builtin_amdgcn_sched_barrier(0); } while (0)

__device__ __forceinline__ void stage_half(const bf16* src, char* lds) {
  gload16(src, lds);
  gload16(src + 64 * 512, lds + 8192);
}
__device__ __forceinline__ void lda4(const bf16* base, int rowbase, int llo,
                                     int xk0, int xk1, s16x8 af[4][2]) {
  #pragma unroll
  for (int mf = 0; mf < 4; mf++) {
    const bf16* p = base + (rowbase + mf * 16 + llo) * 64;
    af[mf][0] = *(const s16x8*)(p + xk0);
    af[mf][1] = *(const s16x8*)(p + xk1);
  }
}
__device__ __forceinline__ void ldb2(const bf16* base, int rowbase, int llo,
                                     int xk0, int xk1, s16x8 bfr[2][2]) {
  #pragma unroll
  for (int nf = 0; nf < 2; nf++) {
    const bf16* p = base + (rowbase + nf * 16 + llo) * 64;
    bfr[nf][0] = *(const s16x8*)(p + xk0);
    bfr[nf][1] = *(const s16x8*)(p + xk1);
  }
}
__device__ __forceinline__ void mma16(f32x4 acc[4][2], s16x8 af[4][2],
                                      s16x8 bfr[2][2]) {
  __builtin_amdgcn_s_setprio(1);
  #pragma unroll
  for (int mf = 0; mf < 4; mf++)
    #pragma unroll
    for (int nf = 0; nf < 2; nf++) {
      acc[mf][nf] = __builtin_amdgcn_mfma_f32_16x16x32_bf16(
          af[mf][0], bfr[nf][0], acc[mf][nf], 0, 0, 0);
      acc[mf][nf] = __builtin_amdgcn_mfma_f32_16x16x32_bf16(
          af[mf][1], bfr[nf][1], acc[mf][nf], 0, 0, 0);
    }
  __builtin_amdgcn_s_setprio(0);
}

__global__ __launch_bounds__(512, 2) void gemm_scores(const bf16* __restrict__ qk,
                                                      bf16* __restrict__ S,
                                                      float* __restrict__ rowsumP) {
  __shared__ bf16 As[2][256 * 64];   // [buf][row*64 + k], halves of 128 rows
  __shared__ bf16 Bs[2][256 * 64];
  const int tid = threadIdx.x;
  const int wave = tid >> 6, lane = tid & 63;
  const int llo = lane & 15, lhi = lane >> 4;
  const int wm = wave >> 2, wn = wave & 3;  // 2 x 4 waves

  const unsigned int lin = blockIdx.x;  // 512 blocks
  const int b = (int)(lin & 7u);        // one batch per XCD (Q+K = 4MB = L2)
  const unsigned int idx = lin >> 3;    // 0..63
  const int row0 = (int)(idx >> 3) * 256;
  const int coltile = (int)(idx & 7u);
  const int col0 = coltile * 256;

  const bf16* Ab = qk + (long long)b * 2048 * 512;                           // Q
  const bf16* Bb = qk + (long long)16384 * 512 + (long long)b * 2048 * 512;  // K

  // per-thread staging constants (pre-swizzled global source, linear LDS dest)
  const int sr = tid >> 3;                         // 0..63
  const int kkofs = ((tid & 7) ^ (sr & 7)) << 3;   // element offset
  const bf16* sA = Ab + (long long)(row0 + sr) * 512 + kkofs;
  const bf16* sB = Bb + (long long)(col0 + sr) * 512 + kkofs;
  const int wofs = wave * 1024;

  // read-side swizzled chunk offsets (elements), k0=0 and k0=32
  const int xk0 = ((lhi ^ (llo & 7)) << 3);
  const int xk1 = (((4 + lhi) ^ (llo & 7)) << 3);

  f32x4 acc[2][2][4][2] = {};   // [qr][qc][mf][nf]
  s16x8 af[4][2], bf0[2][2], bf1[2][2];

  // prologue: t0{Ah0,Bh0,Bh1,Ah1}, t1{Ah0,Bh0}  (queue matches steady state)
  stage_half(sA, (char*)As[0] + wofs);
  stage_half(sB, (char*)Bs[0] + wofs);
  stage_half(sB + 128 * 512, (char*)Bs[0] + 16384 + wofs);
  stage_half(sA + 128 * 512, (char*)As[0] + 16384 + wofs);
  stage_half(sA + 64, (char*)As[1] + wofs);
  stage_half(sB + 64, (char*)Bs[1] + wofs);
  VMW8;  // t0 Ah0,Bh0 landed; 4 half-tiles in flight
  PBAR;

  for (int i = 0; i < 4; ++i) {   // 2 K-tiles per iteration, K=512 -> 8 tiles
    const int kt1 = (2 * i + 1) * 64;
    const int kt2 = (2 * i + 2 < 8) ? (2 * i + 2) * 64 : 448;  // clamp tail
    const int kt3 = (2 * i + 3 < 8) ? (2 * i + 3) * 64 : 448;
    // P1: quadrant (r0,c0) of tile t (buf0)
    lda4(As[0], wm * 64, llo, xk0, xk1, af);
    ldb2(Bs[0], wn * 32, llo, xk0, xk1, bf0);
    stage_half(sB + 128 * 512 + kt1, (char*)Bs[1] + 16384 + wofs);  // t+1 Bh1
    VMW8; PBAR;
    mma16(acc[0][0], af, bf0);
    // P2: (r0,c1)
    ldb2(Bs[0], 128 + wn * 32, llo, xk0, xk1, bf1);
    stage_half(sA + 128 * 512 + kt1, (char*)As[1] + 16384 + wofs);  // t+1 Ah1
    VMW8; PBAR;
    mma16(acc[0][1], af, bf1);
    // P3: (r1,c0)
    lda4(As[0], 128 + wm * 64, llo, xk0, xk1, af);
    stage_half(sA + kt2, (char*)As[0] + wofs);                      // t+2 Ah0
    PBAR;
    mma16(acc[1][0], af, bf0);
    // P4: (r1,c1)
    stage_half(sB + kt2, (char*)Bs[0] + wofs);                      // t+2 Bh0
    VMW8; PBAR;
    mma16(acc[1][1], af, bf1);
    // P5: quadrant (r0,c0) of tile t+1 (buf1)
    lda4(As[1], wm * 64, llo, xk0, xk1, af);
    ldb2(Bs[1], wn * 32, llo, xk0, xk1, bf0);
    stage_half(sB + 128 * 512 + kt2, (char*)Bs[0] + 16384 + wofs);  // t+2 Bh1
    VMW8; PBAR;
    mma16(acc[0][0], af, bf0);
    // P6: (r0,c1)
    ldb2(Bs[1], 128 + wn * 32, llo, xk0, xk1, bf1);
    stage_half(sA + 128 * 512 + kt2, (char*)As[0] + 16384 + wofs);  // t+2 Ah1
    VMW8; PBAR;
    mma16(acc[0][1], af, bf1);
    // P7: (r1,c0)
    lda4(As[1], 128 + wm * 64, llo, xk0, xk1, af);
    stage_half(sA + kt3, (char*)As[1] + wofs);                      // t+3 Ah0
    PBAR;
    mma16(acc[1][0], af, bf0);
    // P8: (r1,c1)
    stage_half(sB + kt3, (char*)Bs[1] + wofs);                      // t+3 Bh0
    VMW8; PBAR;
    mma16(acc[1][1], af, bf1);
  }

  __syncthreads();  // drain leftover tail DMAs before reusing As as scratch

  const float alpha = 0.044194173824159216f;  // 1/sqrt(512)
  bf16* Sb = S + (long long)b * 2048 * 2048;
  #pragma unroll
  for (int qr = 0; qr < 2; qr++)
    #pragma unroll
    for (int qc = 0; qc < 2; qc++)
      #pragma unroll
      for (int mf = 0; mf < 4; mf++)
        #pragma unroll
        for (int nf = 0; nf < 2; nf++) {
          #pragma unroll
          for (int r = 0; r < 4; r++)
            acc[qr][qc][mf][nf][r] = __expf(acc[qr][qc][mf][nf][r] * alpha);
          const int gcol = col0 + qc * 128 + wn * 32 + nf * 16 + llo;
          const int grow0 = row0 + qr * 128 + wm * 64 + mf * 16 + lhi * 4;
          #pragma unroll
          for (int r = 0; r < 4; r++)
            Sb[(long long)(grow0 + r) * 2048 + gcol] =
                __float2bfloat16(acc[qr][qc][mf][nf][r]);
        }

  // row partial sums over this block's 256 cols -> rowsumP[b][coltile8][2048]
  float* psum = (float*)As;  // 4 KB scratch (buffers dead, DMAs drained)
  #pragma unroll
  for (int qr = 0; qr < 2; qr++)
    #pragma unroll
    for (int mf = 0; mf < 4; mf++)
      #pragma unroll
      for (int r = 0; r < 4; r++) {
        float p = acc[qr][0][mf][0][r] + acc[qr][0][mf][1][r] +
                  acc[qr][1][mf][0][r] + acc[qr][1][mf][1][r];
        p += __shfl_xor(p, 1, 64);
        p += __shfl_xor(p, 2, 64);
        p += __shfl_xor(p, 4, 64);
        p += __shfl_xor(p, 8, 64);
        if (llo == 0)
          psum[wn * 256 + qr * 128 + wm * 64 + mf * 16 + lhi * 4 + r] = p;
      }
  __syncthreads();
  if (tid < 256) {
    const float v = psum[tid] + psum[256 + tid] + psum[512 + tid] + psum[768 + tid];
    rowsumP[(long long)(b * 8 + coltile) * 2048 + row0 + tid] = v;
  }
}

// ---------------- reduce: rinv[i] = 1 / sum_t rowsumP[b][t][row]  (t<8 now)
__global__ __launch_bounds__(256) void reduce_rowsum(
    const float* __restrict__ rowsumP, float* __restrict__ rinv) {
  const int i = blockIdx.x * 256 + threadIdx.x;  // 0..16383
  const int b = i >> 11, row = i & 2047;
  const float* p = rowsumP + ((long long)b * 8) * 2048 + row;
  float s = 0.f;
  #pragma unroll
  for (int t = 0; t < 8; t++) s += p[t * 2048];
  rinv[i] = 1.0f / s;
}

// ---------------- PV: out[b] = (P[b] V[b]) * rinv, fp32 out
__global__ __launch_bounds__(256) void gemm_pv(const bf16* __restrict__ S,
                                               const bf16* __restrict__ vt,
                                               const float* __restrict__ rinv,
                                               float* __restrict__ out) {
  __shared__ bf16 As[128 * 64];
  __shared__ bf16 Bs[128 * 64];
  const int tid = threadIdx.x;
  const int wave = tid >> 6, lane = tid & 63;
  const int llo = lane & 15, lhi = lane >> 4;
  const int wm = wave >> 1, wn = wave & 1;

  const unsigned int lin = blockIdx.x;  // 512
  const unsigned int xcd = lin & 7u, idx = lin >> 3;  // idx 0..63
  const int b = (int)xcd;
  const int row0 = (int)(idx >> 2) * 128;   // 16 bm
  const int col0 = (int)(idx & 3u) * 128;   // 4 bn

  const bf16* Ab = S + (long long)b * 2048 * 2048;
  const bf16* Bb = vt + (long long)b * 512 * 2048;

  f32x4 acc[4][4] = {};
  for (int kt = 0; kt < 2048; kt += 64) {
    #pragma unroll
    for (int i = 0; i < 4; i++) {
      const int c = i * 256 + tid;
      const int r = c >> 3, cc = c & 7;
      const int kk = (cc ^ (r & 7)) << 3;
      gload16(Ab + ((long long)(row0 + r) * 2048 + kt + kk),
              (char*)As + (long long)(i * 256 + wave * 64) * 16);
      gload16(Bb + ((long long)(col0 + r) * 2048 + kt + kk),
              (char*)Bs + (long long)(i * 256 + wave * 64) * 16);
    }
    __syncthreads();
    #pragma unroll
    for (int k0 = 0; k0 < 64; k0 += 32) {
      const int xk = ((((k0 >> 3) + lhi) ^ (llo & 7)) << 3);
      s16x8 af[4], bfr[4];
      #pragma unroll
      for (int mf = 0; mf < 4; mf++)
        af[mf] = *(const s16x8*)&As[(wm * 64 + mf * 16 + llo) * 64 + xk];
      #pragma unroll
      for (int nf = 0; nf < 4; nf++)
        bfr[nf] = *(const s16x8*)&Bs[(wn * 64 + nf * 16 + llo) * 64 + xk];
      #pragma unroll
      for (int mf = 0; mf < 4; mf++)
        #pragma unroll
        for (int nf = 0; nf < 4; nf++)
          acc[mf][nf] = __builtin_amdgcn_mfma_f32_16x16x32_bf16(
              af[mf], bfr[nf], acc[mf][nf], 0, 0, 0);
    }
    __syncthreads();
  }

  const float* rs = rinv + (long long)b * 2048;
  float* Ob = out + (long long)b * 2048 * 512;
  #pragma unroll
  for (int mf = 0; mf < 4; mf++) {
    const int grow0 = row0 + wm * 64 + mf * 16 + lhi * 4;
    float iv[4];
    #pragma unroll
    for (int r = 0; r < 4; r++) iv[r] = rs[grow0 + r];
    #pragma unroll
    for (int nf = 0; nf < 4; nf++) {
      const int gcol = col0 + wn * 64 + nf * 16 + llo;
      #pragma unroll
      for (int r = 0; r < 4; r++)
        Ob[(long long)(grow0 + r) * 512 + gcol] = acc[mf][nf][r] * iv[r];
    }
  }
}

extern "C" void kernel_launch(void* const* d_in, const int* in_sizes, int n_in,
                              void* d_out, int out_size, void* d_ws, size_t ws_size,
                              hipStream_t stream) {
  const float* patches = (const float*)d_in[0];
  const float* positions = (const float*)d_in[1];
  const float* Wq = (const float*)d_in[2];
  const float* bq = (const float*)d_in[3];
  const float* Wk = (const float*)d_in[4];
  const float* bk = (const float*)d_in[5];
  const float* Wv = (const float*)d_in[6];
  const float* bv = (const float*)d_in[7];
  float* out = (float*)d_out;

  if (ws_size < 149422080u) return;

  char* ws = (char*)d_ws;
  bf16* Wt = (bf16*)(ws);                    // 3*512*832*2   = 2,555,904
  bf16* xb = (bf16*)(ws + 2555904);          // 16384*832*2   = 27,262,976
  bf16* qk = (bf16*)(ws + 29818880);         // 2*16384*512*2 = 33,554,432 (Q,K)
  bf16* vt = (bf16*)(ws + 63373312);         // 8*512*2048*2  = 16,777,216 (V^T)
  bf16* S  = (bf16*)(ws + 80150528);         // 8*2048*2048*2 = 67,108,864
  float* rinv    = (float*)(ws + 147259392); // 16384*4       = 65,536
  float* rowsumP = (float*)(ws + 147324928); // 8*8*2048*4    = 524,288

  prep_x<<<16384, 256, 0, stream>>>(patches, positions, xb);
  prep_w<<<dim3(16, 26, 3), dim3(32, 8), 0, stream>>>(Wq, Wk, Wv, Wt);
  gemm_qkv<<<1536, 256, 0, stream>>>(xb, Wt, bq, bk, bv, qk, vt);
  gemm_scores<<<512, 512, 0, stream>>>(qk, S, rowsumP);
  reduce_rowsum<<<64, 256, 0, stream>>>(rowsumP, rinv);
  gemm_pv<<<512, 256, 0, stream>>>(S, vt, rinv, out);
}

// Round 2
// 261.576 us; speedup vs baseline: 1.0429x; 1.0416x over previous
//
#include <hip/hip_runtime.h>
#include <hip/hip_bf16.h>
#include <math.h>

typedef __hip_bfloat16 bf16;
typedef __attribute__((ext_vector_type(4))) float f32x4;
typedef __attribute__((ext_vector_type(8))) short s16x8;

typedef const __attribute__((address_space(1))) void gvoid_t;
typedef __attribute__((address_space(3))) void lvoid_t;

__device__ __forceinline__ void gload16(const void* g, void* l) {
  // async global->LDS, 16B/lane; LDS dest is wave-uniform base + lane*16
  __builtin_amdgcn_global_load_lds((gvoid_t*)g, (lvoid_t*)l, 16, 0, 0);
}
__device__ __forceinline__ unsigned short f2b(float f) {
  bf16 h = __float2bfloat16(f);
  return *(unsigned short*)&h;
}

// ---------------- prep: x = concat(patches, positions) -> bf16 [16384][832]
__global__ __launch_bounds__(256) void prep_x(const float* __restrict__ patches,
                                              const float* __restrict__ positions,
                                              bf16* __restrict__ xb) {
  const long long row = blockIdx.x;
  const int c = threadIdx.x;
  const bool lo = (c < 192);
  const bool hi = (c >= 192) && (c < 208);
  const float* src = lo ? (patches + row * 768 + c * 4)
                        : (positions + row * 64 + (c - 192) * 4);
  if (lo || hi) {
    float4 v = *(const float4*)src;
    const int dst = lo ? (c * 4) : (768 + (c - 192) * 4);
    uint2 w;
    w.x = (unsigned int)f2b(v.x) | ((unsigned int)f2b(v.y) << 16);
    w.y = (unsigned int)f2b(v.z) | ((unsigned int)f2b(v.w) << 16);
    *(uint2*)(xb + row * 832 + dst) = w;
  }
}

// ---------------- prep: Wt[z*512+n][k] = W_z[k][n] bf16 (832x512 -> 512x832)
__global__ __launch_bounds__(256) void prep_w(const float* __restrict__ Wq,
                                              const float* __restrict__ Wk,
                                              const float* __restrict__ Wv,
                                              bf16* __restrict__ Wt) {
  __shared__ float tile[32][33];
  const int z = blockIdx.z;
  const float* W = (z == 0) ? Wq : (z == 1) ? Wk : Wv;
  bf16* T = Wt + (long long)z * 512 * 832;
  const int n0 = blockIdx.x * 32;
  const int k0 = blockIdx.y * 32;
  const int tx = threadIdx.x, ty = threadIdx.y;  // (32,8)
  #pragma unroll
  for (int i = 0; i < 32; i += 8)
    tile[ty + i][tx] = W[(long long)(k0 + ty + i) * 512 + n0 + tx];
  __syncthreads();
  #pragma unroll
  for (int i = 0; i < 32; i += 8)
    T[(long long)(n0 + ty + i) * 832 + k0 + tx] = __float2bfloat16(tile[tx][ty + i]);
}

// ================ shared 8-phase template pieces (verified in gemm_scores) ==
// vmcnt(8) = 4 half-tiles (2 gloads/thread each) stay in flight; never 0 in
// the main loop. PBAR = barrier + scheduler fence so phases can't bleed.
#define VMW8 asm volatile("s_waitcnt vmcnt(8)" ::: "memory")
#define PBAR do { __builtin_amdgcn_s_barrier(); __builtin_amdgcn_sched_barrier(0); } while (0)

__device__ __forceinline__ void stage_half(const bf16* src, char* lds, int stride) {
  gload16(src, lds);                       // rows r..r+63 of the 128-row half
  gload16(src + 64 * stride, lds + 8192);  // rows r+64..r+127
}
__device__ __forceinline__ void lda4(const bf16* base, int rowbase, int llo,
                                     int xk0, int xk1, s16x8 af[4][2]) {
  #pragma unroll
  for (int mf = 0; mf < 4; mf++) {
    const bf16* p = base + (rowbase + mf * 16 + llo) * 64;
    af[mf][0] = *(const s16x8*)(p + xk0);
    af[mf][1] = *(const s16x8*)(p + xk1);
  }
}
__device__ __forceinline__ void ldb2(const bf16* base, int rowbase, int llo,
                                     int xk0, int xk1, s16x8 bfr[2][2]) {
  #pragma unroll
  for (int nf = 0; nf < 2; nf++) {
    const bf16* p = base + (rowbase + nf * 16 + llo) * 64;
    bfr[nf][0] = *(const s16x8*)(p + xk0);
    bfr[nf][1] = *(const s16x8*)(p + xk1);
  }
}
__device__ __forceinline__ void mma16(f32x4 acc[4][2], s16x8 af[4][2],
                                      s16x8 bfr[2][2]) {
  __builtin_amdgcn_s_setprio(1);
  #pragma unroll
  for (int mf = 0; mf < 4; mf++)
    #pragma unroll
    for (int nf = 0; nf < 2; nf++) {
      acc[mf][nf] = __builtin_amdgcn_mfma_f32_16x16x32_bf16(
          af[mf][0], bfr[nf][0], acc[mf][nf], 0, 0, 0);
      acc[mf][nf] = __builtin_amdgcn_mfma_f32_16x16x32_bf16(
          af[mf][1], bfr[nf][1], acc[mf][nf], 0, 0, 0);
    }
  __builtin_amdgcn_s_setprio(0);
}

// ---------------- fused QKV projection: [16384,832] x [1536,832]^T
// 256x256 tile, 8 waves, 8-phase counted-vmcnt schedule (same template as
// gemm_scores). K=832 = 13 BK=64 tiles: 6 loop iters (2 tiles each) + tail
// tile 12; tail prefetches clamp to tile 12 (dup into dead buf1, never read).
__global__ __launch_bounds__(512, 2) void gemm_qkv(
    const bf16* __restrict__ xb, const bf16* __restrict__ Wt,
    const float* __restrict__ bq, const float* __restrict__ bk,
    const float* __restrict__ bv,
    bf16* __restrict__ qk, bf16* __restrict__ vt) {
  __shared__ bf16 As[2][256 * 64];
  __shared__ bf16 Bs[2][256 * 64];
  const int tid = threadIdx.x;
  const int wave = tid >> 6, lane = tid & 63;
  const int llo = lane & 15, lhi = lane >> 4;
  const int wm = wave >> 2, wn = wave & 3;  // 2 x 4 waves

  const unsigned int lin = blockIdx.x;      // 384 blocks (384%8==0, bijective)
  const unsigned int xcd = lin & 7u, idx = lin >> 3;  // idx 0..47
  const unsigned int g = xcd * 48u + idx;
  const unsigned int bm_t = g / 6u;         // 0..63
  const unsigned int bn_t = g - bm_t * 6u;  // 0..5
  const int row0 = (int)bm_t * 256;
  const int col0 = (int)bn_t * 256;
  const int z = col0 >> 9;                  // 256-col tiles never straddle z

  // staging: pre-swizzled global source, linear LDS dest (rule 21 pair)
  const int sr = tid >> 3;                        // 0..63
  const int kkofs = ((tid & 7) ^ (sr & 7)) << 3;  // element offset
  const bf16* sA = xb + (long long)(row0 + sr) * 832 + kkofs;
  const bf16* sB = Wt + (long long)(col0 + sr) * 832 + kkofs;
  const int wofs = wave * 1024;

  // read-side swizzled chunk offsets (elements), k0=0 and k0=32
  const int xk0 = ((lhi ^ (llo & 7)) << 3);
  const int xk1 = (((4 + lhi) ^ (llo & 7)) << 3);

  f32x4 acc[2][2][4][2] = {};  // [qr][qc][mf][nf]
  s16x8 af[4][2], bf0[2][2], bf1[2][2];

  // prologue: t0{Ah0,Bh0,Bh1,Ah1}, t1{Ah0,Bh0} -> 12 loads; vm(8) retires
  // t0 h0 halves (4 oldest), 4 half-tiles stay in flight.
  stage_half(sA, (char*)As[0] + wofs, 832);
  stage_half(sB, (char*)Bs[0] + wofs, 832);
  stage_half(sB + 128 * 832, (char*)Bs[0] + 16384 + wofs, 832);
  stage_half(sA + 128 * 832, (char*)As[0] + 16384 + wofs, 832);
  stage_half(sA + 64, (char*)As[1] + wofs, 832);
  stage_half(sB + 64, (char*)Bs[1] + wofs, 832);
  VMW8; PBAR;

  for (int i = 0; i < 6; ++i) {  // tiles 2i (buf0), 2i+1 (buf1)
    const int kt1 = (2 * i + 1) * 64;
    const int kt2 = (2 * i + 2 <= 12) ? (2 * i + 2) * 64 : 768;  // clamp tail
    const int kt3 = (2 * i + 3 <= 12) ? (2 * i + 3) * 64 : 768;
    // P1: quadrant (r0,c0) of tile t (buf0)
    lda4(As[0], wm * 64, llo, xk0, xk1, af);
    ldb2(Bs[0], wn * 32, llo, xk0, xk1, bf0);
    stage_half(sB + 128 * 832 + kt1, (char*)Bs[1] + 16384 + wofs, 832);
    VMW8; PBAR;
    mma16(acc[0][0], af, bf0);
    // P2: (r0,c1)
    ldb2(Bs[0], 128 + wn * 32, llo, xk0, xk1, bf1);
    stage_half(sA + 128 * 832 + kt1, (char*)As[1] + 16384 + wofs, 832);
    VMW8; PBAR;
    mma16(acc[0][1], af, bf1);
    // P3: (r1,c0)
    lda4(As[0], 128 + wm * 64, llo, xk0, xk1, af);
    stage_half(sA + kt2, (char*)As[0] + wofs, 832);
    PBAR;
    mma16(acc[1][0], af, bf0);
    // P4: (r1,c1)
    stage_half(sB + kt2, (char*)Bs[0] + wofs, 832);
    VMW8; PBAR;
    mma16(acc[1][1], af, bf1);
    // P5: quadrant (r0,c0) of tile t+1 (buf1)
    lda4(As[1], wm * 64, llo, xk0, xk1, af);
    ldb2(Bs[1], wn * 32, llo, xk0, xk1, bf0);
    stage_half(sB + 128 * 832 + kt2, (char*)Bs[0] + 16384 + wofs, 832);
    VMW8; PBAR;
    mma16(acc[0][0], af, bf0);
    // P6: (r0,c1)
    ldb2(Bs[1], 128 + wn * 32, llo, xk0, xk1, bf1);
    stage_half(sA + 128 * 832 + kt2, (char*)As[0] + 16384 + wofs, 832);
    VMW8; PBAR;
    mma16(acc[0][1], af, bf1);
    // P7: (r1,c0)
    lda4(As[1], 128 + wm * 64, llo, xk0, xk1, af);
    stage_half(sA + kt3, (char*)As[1] + wofs, 832);
    PBAR;
    mma16(acc[1][0], af, bf0);
    // P8: (r1,c1)
    stage_half(sB + kt3, (char*)Bs[1] + wofs, 832);
    VMW8; PBAR;
    mma16(acc[1][1], af, bf1);
  }

  // tail: tile 12 (buf0). Outstanding: {t12 Bh1, t12 Ah1, dupAh0, dupBh0};
  // vm(4) retires t12's h1 halves; dups land in buf1 (never read).
  asm volatile("s_waitcnt vmcnt(4)" ::: "memory");
  PBAR;
  lda4(As[0], wm * 64, llo, xk0, xk1, af);
  ldb2(Bs[0], wn * 32, llo, xk0, xk1, bf0);
  ldb2(Bs[0], 128 + wn * 32, llo, xk0, xk1, bf1);
  mma16(acc[0][0], af, bf0);
  mma16(acc[0][1], af, bf1);
  lda4(As[0], 128 + wm * 64, llo, xk0, xk1, af);
  mma16(acc[1][0], af, bf0);
  mma16(acc[1][1], af, bf1);

  // epilogue: C/D layout col=lane&15, row=(lane>>4)*4+reg
  if (z < 2) {
    const float* bias = z ? bk : bq;
    bf16* outp = qk + (long long)z * 16384 * 512;
    #pragma unroll
    for (int qr = 0; qr < 2; qr++)
      #pragma unroll
      for (int qc = 0; qc < 2; qc++)
        #pragma unroll
        for (int mf = 0; mf < 4; mf++)
          #pragma unroll
          for (int nf = 0; nf < 2; nf++) {
            const int c = (col0 & 511) + qc * 128 + wn * 32 + nf * 16 + llo;
            const int grow0 = row0 + qr * 128 + wm * 64 + mf * 16 + lhi * 4;
            const float bb = bias[c];
            #pragma unroll
            for (int r = 0; r < 4; r++)
              outp[(long long)(grow0 + r) * 512 + c] =
                  __float2bfloat16(acc[qr][qc][mf][nf][r] + bb);
          }
  } else {
    #pragma unroll
    for (int qr = 0; qr < 2; qr++)
      #pragma unroll
      for (int qc = 0; qc < 2; qc++)
        #pragma unroll
        for (int mf = 0; mf < 4; mf++)
          #pragma unroll
          for (int nf = 0; nf < 2; nf++) {
            const int c = (col0 & 511) + qc * 128 + wn * 32 + nf * 16 + llo;
            const int grow0 = row0 + qr * 128 + wm * 64 + mf * 16 + lhi * 4;
            const int b = grow0 >> 11, j = grow0 & 2047;
            const float bb = bv[c];
            uint2 w;
            w.x = (unsigned int)f2b(acc[qr][qc][mf][nf][0] + bb) |
                  ((unsigned int)f2b(acc[qr][qc][mf][nf][1] + bb) << 16);
            w.y = (unsigned int)f2b(acc[qr][qc][mf][nf][2] + bb) |
                  ((unsigned int)f2b(acc[qr][qc][mf][nf][3] + bb) << 16);
            *(uint2*)(vt + (long long)b * 512 * 2048 + (long long)c * 2048 + j) = w;
          }
  }
}

// ---------------- scores+exp: 256x256 tile, 8 waves, 8-phase counted-vmcnt
// (passed round 1; unchanged)
__global__ __launch_bounds__(512, 2) void gemm_scores(const bf16* __restrict__ qk,
                                                      bf16* __restrict__ S,
                                                      float* __restrict__ rowsumP) {
  __shared__ bf16 As[2][256 * 64];
  __shared__ bf16 Bs[2][256 * 64];
  const int tid = threadIdx.x;
  const int wave = tid >> 6, lane = tid & 63;
  const int llo = lane & 15, lhi = lane >> 4;
  const int wm = wave >> 2, wn = wave & 3;  // 2 x 4 waves

  const unsigned int lin = blockIdx.x;  // 512 blocks
  const int b = (int)(lin & 7u);        // one batch per XCD (Q+K = 4MB = L2)
  const unsigned int idx = lin >> 3;    // 0..63
  const int row0 = (int)(idx >> 3) * 256;
  const int coltile = (int)(idx & 7u);
  const int col0 = coltile * 256;

  const bf16* Ab = qk + (long long)b * 2048 * 512;                           // Q
  const bf16* Bb = qk + (long long)16384 * 512 + (long long)b * 2048 * 512;  // K

  const int sr = tid >> 3;
  const int kkofs = ((tid & 7) ^ (sr & 7)) << 3;
  const bf16* sA = Ab + (long long)(row0 + sr) * 512 + kkofs;
  const bf16* sB = Bb + (long long)(col0 + sr) * 512 + kkofs;
  const int wofs = wave * 1024;

  const int xk0 = ((lhi ^ (llo & 7)) << 3);
  const int xk1 = (((4 + lhi) ^ (llo & 7)) << 3);

  f32x4 acc[2][2][4][2] = {};   // [qr][qc][mf][nf]
  s16x8 af[4][2], bf0[2][2], bf1[2][2];

  stage_half(sA, (char*)As[0] + wofs, 512);
  stage_half(sB, (char*)Bs[0] + wofs, 512);
  stage_half(sB + 128 * 512, (char*)Bs[0] + 16384 + wofs, 512);
  stage_half(sA + 128 * 512, (char*)As[0] + 16384 + wofs, 512);
  stage_half(sA + 64, (char*)As[1] + wofs, 512);
  stage_half(sB + 64, (char*)Bs[1] + wofs, 512);
  VMW8; PBAR;

  for (int i = 0; i < 4; ++i) {   // 2 K-tiles per iteration, K=512 -> 8 tiles
    const int kt1 = (2 * i + 1) * 64;
    const int kt2 = (2 * i + 2 < 8) ? (2 * i + 2) * 64 : 448;  // clamp tail
    const int kt3 = (2 * i + 3 < 8) ? (2 * i + 3) * 64 : 448;
    // P1
    lda4(As[0], wm * 64, llo, xk0, xk1, af);
    ldb2(Bs[0], wn * 32, llo, xk0, xk1, bf0);
    stage_half(sB + 128 * 512 + kt1, (char*)Bs[1] + 16384 + wofs, 512);
    VMW8; PBAR;
    mma16(acc[0][0], af, bf0);
    // P2
    ldb2(Bs[0], 128 + wn * 32, llo, xk0, xk1, bf1);
    stage_half(sA + 128 * 512 + kt1, (char*)As[1] + 16384 + wofs, 512);
    VMW8; PBAR;
    mma16(acc[0][1], af, bf1);
    // P3
    lda4(As[0], 128 + wm * 64, llo, xk0, xk1, af);
    stage_half(sA + kt2, (char*)As[0] + wofs, 512);
    PBAR;
    mma16(acc[1][0], af, bf0);
    // P4
    stage_half(sB + kt2, (char*)Bs[0] + wofs, 512);
    VMW8; PBAR;
    mma16(acc[1][1], af, bf1);
    // P5
    lda4(As[1], wm * 64, llo, xk0, xk1, af);
    ldb2(Bs[1], wn * 32, llo, xk0, xk1, bf0);
    stage_half(sB + 128 * 512 + kt2, (char*)Bs[0] + 16384 + wofs, 512);
    VMW8; PBAR;
    mma16(acc[0][0], af, bf0);
    // P6
    ldb2(Bs[1], 128 + wn * 32, llo, xk0, xk1, bf1);
    stage_half(sA + 128 * 512 + kt2, (char*)As[0] + 16384 + wofs, 512);
    VMW8; PBAR;
    mma16(acc[0][1], af, bf1);
    // P7
    lda4(As[1], 128 + wm * 64, llo, xk0, xk1, af);
    stage_half(sA + kt3, (char*)As[1] + wofs, 512);
    PBAR;
    mma16(acc[1][0], af, bf0);
    // P8
    stage_half(sB + kt3, (char*)Bs[1] + wofs, 512);
    VMW8; PBAR;
    mma16(acc[1][1], af, bf1);
  }

  __syncthreads();  // drain leftover tail DMAs before reusing As as scratch

  const float alpha = 0.044194173824159216f;  // 1/sqrt(512)
  bf16* Sb = S + (long long)b * 2048 * 2048;
  #pragma unroll
  for (int qr = 0; qr < 2; qr++)
    #pragma unroll
    for (int qc = 0; qc < 2; qc++)
      #pragma unroll
      for (int mf = 0; mf < 4; mf++)
        #pragma unroll
        for (int nf = 0; nf < 2; nf++) {
          #pragma unroll
          for (int r = 0; r < 4; r++)
            acc[qr][qc][mf][nf][r] = __expf(acc[qr][qc][mf][nf][r] * alpha);
          const int gcol = col0 + qc * 128 + wn * 32 + nf * 16 + llo;
          const int grow0 = row0 + qr * 128 + wm * 64 + mf * 16 + lhi * 4;
          #pragma unroll
          for (int r = 0; r < 4; r++)
            Sb[(long long)(grow0 + r) * 2048 + gcol] =
                __float2bfloat16(acc[qr][qc][mf][nf][r]);
        }

  float* psum = (float*)As;  // 4 KB scratch (buffers dead, DMAs drained)
  #pragma unroll
  for (int qr = 0; qr < 2; qr++)
    #pragma unroll
    for (int mf = 0; mf < 4; mf++)
      #pragma unroll
      for (int r = 0; r < 4; r++) {
        float p = acc[qr][0][mf][0][r] + acc[qr][0][mf][1][r] +
                  acc[qr][1][mf][0][r] + acc[qr][1][mf][1][r];
        p += __shfl_xor(p, 1, 64);
        p += __shfl_xor(p, 2, 64);
        p += __shfl_xor(p, 4, 64);
        p += __shfl_xor(p, 8, 64);
        if (llo == 0)
          psum[wn * 256 + qr * 128 + wm * 64 + mf * 16 + lhi * 4 + r] = p;
      }
  __syncthreads();
  if (tid < 256) {
    const float v = psum[tid] + psum[256 + tid] + psum[512 + tid] + psum[768 + tid];
    rowsumP[(long long)(b * 8 + coltile) * 2048 + row0 + tid] = v;
  }
}

// ---------------- reduce: rinv[i] = 1 / sum_t rowsumP[b][t][row]
__global__ __launch_bounds__(256) void reduce_rowsum(
    const float* __restrict__ rowsumP, float* __restrict__ rinv) {
  const int i = blockIdx.x * 256 + threadIdx.x;  // 0..16383
  const int b = i >> 11, row = i & 2047;
  const float* p = rowsumP + ((long long)b * 8) * 2048 + row;
  float s = 0.f;
  #pragma unroll
  for (int t = 0; t < 8; t++) s += p[t * 2048];
  rinv[i] = 1.0f / s;
}

// ---------------- PV: out[b] = (P[b] V[b]) * rinv, fp32 out
__global__ __launch_bounds__(256) void gemm_pv(const bf16* __restrict__ S,
                                               const bf16* __restrict__ vt,
                                               const float* __restrict__ rinv,
                                               float* __restrict__ out) {
  __shared__ bf16 As[128 * 64];
  __shared__ bf16 Bs[128 * 64];
  const int tid = threadIdx.x;
  const int wave = tid >> 6, lane = tid & 63;
  const int llo = lane & 15, lhi = lane >> 4;
  const int wm = wave >> 1, wn = wave & 1;

  const unsigned int lin = blockIdx.x;  // 512
  const unsigned int xcd = lin & 7u, idx = lin >> 3;  // idx 0..63
  const int b = (int)xcd;
  const int row0 = (int)(idx >> 2) * 128;   // 16 bm
  const int col0 = (int)(idx & 3u) * 128;   // 4 bn

  const bf16* Ab = S + (long long)b * 2048 * 2048;
  const bf16* Bb = vt + (long long)b * 512 * 2048;

  f32x4 acc[4][4] = {};
  for (int kt = 0; kt < 2048; kt += 64) {
    #pragma unroll
    for (int i = 0; i < 4; i++) {
      const int c = i * 256 + tid;
      const int r = c >> 3, cc = c & 7;
      const int kk = (cc ^ (r & 7)) << 3;
      gload16(Ab + ((long long)(row0 + r) * 2048 + kt + kk),
              (char*)As + (long long)(i * 256 + wave * 64) * 16);
      gload16(Bb + ((long long)(col0 + r) * 2048 + kt + kk),
              (char*)Bs + (long long)(i * 256 + wave * 64) * 16);
    }
    __syncthreads();
    #pragma unroll
    for (int k0 = 0; k0 < 64; k0 += 32) {
      const int xk = ((((k0 >> 3) + lhi) ^ (llo & 7)) << 3);
      s16x8 af[4], bfr[4];
      #pragma unroll
      for (int mf = 0; mf < 4; mf++)
        af[mf] = *(const s16x8*)&As[(wm * 64 + mf * 16 + llo) * 64 + xk];
      #pragma unroll
      for (int nf = 0; nf < 4; nf++)
        bfr[nf] = *(const s16x8*)&Bs[(wn * 64 + nf * 16 + llo) * 64 + xk];
      #pragma unroll
      for (int mf = 0; mf < 4; mf++)
        #pragma unroll
        for (int nf = 0; nf < 4; nf++)
          acc[mf][nf] = __builtin_amdgcn_mfma_f32_16x16x32_bf16(
              af[mf], bfr[nf], acc[mf][nf], 0, 0, 0);
    }
    __syncthreads();
  }

  const float* rs = rinv + (long long)b * 2048;
  float* Ob = out + (long long)b * 2048 * 512;
  #pragma unroll
  for (int mf = 0; mf < 4; mf++) {
    const int grow0 = row0 + wm * 64 + mf * 16 + lhi * 4;
    float iv[4];
    #pragma unroll
    for (int r = 0; r < 4; r++) iv[r] = rs[grow0 + r];
    #pragma unroll
    for (int nf = 0; nf < 4; nf++) {
      const int gcol = col0 + wn * 64 + nf * 16 + llo;
      #pragma unroll
      for (int r = 0; r < 4; r++)
        Ob[(long long)(grow0 + r) * 512 + gcol] = acc[mf][nf][r] * iv[r];
    }
  }
}

extern "C" void kernel_launch(void* const* d_in, const int* in_sizes, int n_in,
                              void* d_out, int out_size, void* d_ws, size_t ws_size,
                              hipStream_t stream) {
  const float* patches = (const float*)d_in[0];
  const float* positions = (const float*)d_in[1];
  const float* Wq = (const float*)d_in[2];
  const float* bq = (const float*)d_in[3];
  const float* Wk = (const float*)d_in[4];
  const float* bk = (const float*)d_in[5];
  const float* Wv = (const float*)d_in[6];
  const float* bv = (const float*)d_in[7];
  float* out = (float*)d_out;

  if (ws_size < 149422080u) return;

  char* ws = (char*)d_ws;
  bf16* Wt = (bf16*)(ws);                    // 3*512*832*2   = 2,555,904
  bf16* xb = (bf16*)(ws + 2555904);          // 16384*832*2   = 27,262,976
  bf16* qk = (bf16*)(ws + 29818880);         // 2*16384*512*2 = 33,554,432 (Q,K)
  bf16* vt = (bf16*)(ws + 63373312);         // 8*512*2048*2  = 16,777,216 (V^T)
  bf16* S  = (bf16*)(ws + 80150528);         // 8*2048*2048*2 = 67,108,864
  float* rinv    = (float*)(ws + 147259392); // 16384*4       = 65,536
  float* rowsumP = (float*)(ws + 147324928); // 8*8*2048*4    = 524,288

  prep_x<<<16384, 256, 0, stream>>>(patches, positions, xb);
  prep_w<<<dim3(16, 26, 3), dim3(32, 8), 0, stream>>>(Wq, Wk, Wv, Wt);
  gemm_qkv<<<384, 512, 0, stream>>>(xb, Wt, bq, bk, bv, qk, vt);
  gemm_scores<<<512, 512, 0, stream>>>(qk, S, rowsumP);
  reduce_rowsum<<<64, 256, 0, stream>>>(rowsumP, rinv);
  gemm_pv<<<512, 256, 0, stream>>>(S, vt, rinv, out);
}